// Round 4
// baseline (468.632 us; speedup 1.0000x reference)
//
#include <hip/hip_runtime.h>
#include <hip/hip_fp8.h>
#include <cstdio>
#include <cstdint>

#define K_DIM 4096
#define N_DIM 4096
#define BKB 64                 // K-bytes per LDS tile
#define NT (K_DIM / BKB)       // 64 K-tiles

typedef int v4i __attribute__((ext_vector_type(4)));
typedef int v8i __attribute__((ext_vector_type(8)));
typedef float v16f __attribute__((ext_vector_type(16)));

// ---------------------------------------------------------------- amax ------
__global__ void amax_kernel(const float4* __restrict__ x, int n4,
                            unsigned* __restrict__ out) {
  int i = blockIdx.x * blockDim.x + threadIdx.x;
  int stride = gridDim.x * blockDim.x;
  float m = 0.f;
  for (; i < n4; i += stride) {
    float4 v = x[i];
    m = fmaxf(m, fmaxf(fmaxf(fabsf(v.x), fabsf(v.y)),
                       fmaxf(fabsf(v.z), fabsf(v.w))));
  }
#pragma unroll
  for (int off = 32; off > 0; off >>= 1)
    m = fmaxf(m, __shfl_down(m, off, 64));
  __shared__ float wred[4];
  int lane = threadIdx.x & 63, wid = threadIdx.x >> 6;
  if (lane == 0) wred[wid] = m;
  __syncthreads();
  if (threadIdx.x == 0) {
    m = fmaxf(fmaxf(wred[0], wred[1]), fmaxf(wred[2], wred[3]));
    atomicMax(out, __float_as_uint(m));  // bit-compare valid: m >= 0
  }
}

__device__ __forceinline__ float load_scale(const unsigned* p) {
  return fmaxf(__uint_as_float(*p) / 448.0f, 1e-12f);
}

__device__ __forceinline__ unsigned f2fp8(float v) {
  return (unsigned)__hip_cvt_float_to_fp8(v, __HIP_SATFINITE, __HIP_E4M3);
}

// ------------------------------------------------------------- quantize A ---
__global__ void quant1_kernel(const float4* __restrict__ x, uint4* __restrict__ q,
                              const unsigned* __restrict__ amax_bits, int n16) {
  float s = load_scale(amax_bits);
  int i = blockIdx.x * blockDim.x + threadIdx.x;
  int stride = gridDim.x * blockDim.x;
  for (; i < n16; i += stride) {
    unsigned w[4];
#pragma unroll
    for (int j = 0; j < 4; ++j) {
      float4 v = x[i * 4 + j];
      w[j] = f2fp8(v.x / s) | (f2fp8(v.y / s) << 8) |
             (f2fp8(v.z / s) << 16) | (f2fp8(v.w / s) << 24);
    }
    uint4 r; r.x = w[0]; r.y = w[1]; r.z = w[2]; r.w = w[3];
    q[i] = r;
  }
}

// -------------------------------------------- quantize + transpose B --------
__global__ void quant2t_kernel(const float* __restrict__ x,
                               unsigned char* __restrict__ qt,
                               const unsigned* __restrict__ amax_bits) {
  float s = load_scale(amax_bits);
  __shared__ unsigned char tile[64][68];
  int tj = blockIdx.x & 63;
  int ti = blockIdx.x >> 6;
  int t = threadIdx.x;
  int c = t & 63;
  int r0 = (t >> 6) * 16;
#pragma unroll
  for (int rr = 0; rr < 16; ++rr) {
    int r = r0 + rr;
    float v = x[(size_t)(ti * 64 + r) * N_DIM + tj * 64 + c];
    tile[c][r] = (unsigned char)f2fp8(v / s);
  }
  __syncthreads();
  int n = t >> 2;
  int kc = (t & 3) << 4;
  const unsigned* lp = (const unsigned*)&tile[n][kc];
  uint4 v; v.x = lp[0]; v.y = lp[1]; v.z = lp[2]; v.w = lp[3];
  *(uint4*)&qt[(size_t)(tj * 64 + n) * K_DIM + ti * 64 + kc] = v;
}

// ------------------------------------------------------------------ GEMM ----
// 256x256 tile, 8 waves (2Mx4N), BK=64B, ring-4 LDS, MX-scaled fp8 MFMA
// (scale exp 127 => exact 1.0) at 2x the non-scaled fp8 rate.
// Schedule: 2 phases/tile, fragment reads pipelined ONE PHASE AHEAD, one
// barrier per tile, counted vmcnt(4) at the boundary (never drains the
// prefetch queue). Cross-wave visibility of tile X's staged data is
// established at the barrier ONE TILE BEFORE any wave reads X's fragments.
#define GLOAD(src, dst)                                              \
  __builtin_amdgcn_global_load_lds(                                  \
      (const __attribute__((address_space(1))) void*)(src),          \
      (__attribute__((address_space(3))) void*)(dst), 16, 0, 0)

#define MFMA_SC(a, b, c)                                             \
  __builtin_amdgcn_mfma_scale_f32_32x32x64_f8f6f4(a, b, c, 0, 0, 0, 127, 0, 127)

__global__ __launch_bounds__(512, 2)
void gemm_fp8_kernel(const unsigned char* __restrict__ A,
                     const unsigned char* __restrict__ Bt,
                     float* __restrict__ C,
                     const unsigned* __restrict__ amax_bits) {
  __shared__ __align__(16) unsigned char lds[4][32768];

  int bid = blockIdx.x;
  int nwg = gridDim.x;                    // 1024, %8 == 0
  int swz = (bid & 7) * (nwg >> 3) + (bid >> 3);
  int brow = (swz >> 4) * 256;
  int bcol = (swz & 15) * 256;

  int t = threadIdx.x;
  int lane = t & 63, wid = t >> 6;
  int wm = wid >> 2, wn = wid & 3;        // wave quadrant: 2M x 4N
  int r5 = lane & 31;                     // row/col within 32x32 subtile
  int khalf = lane >> 5;                  // k-half selector (32B each)

  // staging: dest linear (t*16), source column pre-swizzled (involution)
  int su = (t & 7) ^ ((t >> 3) & 7);
  int srow = 2 * (t >> 3) + (su >> 2);
  int scol = (su & 3) << 4;
  int sdst = t << 4;
  const unsigned char* gA0 = A + (size_t)(brow + srow) * K_DIM + scol;
  const unsigned char* gA1 = gA0 + (size_t)128 * K_DIM;
  const unsigned char* gB0 = Bt + (size_t)(bcol + srow) * K_DIM + scol;
  const unsigned char* gB1 = gB0 + (size_t)128 * K_DIM;

  // fragment reads: lane reads row base+r5, bytes khalf*32..+31 as two b128
  // at swizzled 16B slots (slot1 == slot0 ^ 16).
  int kq0 = khalf << 1;
  int mac = (r5 >> 1) & 7;
  int slot0 = (((((r5 & 1) << 2) | kq0) ^ mac) << 4);
  int slot1 = (((((r5 & 1) << 2) | (kq0 + 1)) ^ mac) << 4);
  int arow = (wm * 64 + (r5 >> 1)) * 128;           // + m*2048 per subtile
  int brow_o = 16384 + (wn * 32 + (r5 >> 1)) * 128; // + n*2048 per subtile

  auto STAGE = [&](int T, int part) {
    unsigned char* dst = &lds[T & 3][part * 8192] + sdst;
    int koff = T * BKB;
    const unsigned char* src = part == 0   ? gA0 + koff
                               : part == 1 ? gA1 + koff
                               : part == 2 ? gB0 + koff
                                           : gB1 + koff;
    GLOAD(src, dst);
  };

  auto FRAG = [&](const unsigned char* buf, int base) -> v8i {
    v4i lo = *(const v4i*)(buf + base + slot0);
    v4i hi = *(const v4i*)(buf + base + slot1);
    return __builtin_shufflevector(lo, hi, 0, 1, 2, 3, 4, 5, 6, 7);
  };

  v16f acc[4][2] = {};

  // prologue: stage tiles 0,1,2; drain so tiles 0 AND 1 have landed (tile 1's
  // frags are read during tile 0 phase 1); barrier publishes across waves.
#pragma unroll
  for (int T = 0; T < 3; ++T)
#pragma unroll
    for (int p = 0; p < 4; ++p) STAGE(T, p);
  asm volatile("s_waitcnt vmcnt(4)" ::: "memory");
  __builtin_amdgcn_s_barrier();

  v8i a0 = FRAG(lds[0], arow);
  v8i a1 = FRAG(lds[0], arow + 2048);
  v8i b0 = FRAG(lds[0], brow_o);
  v8i b1 = FRAG(lds[0], brow_o + 2048);

  for (int T = 0; T < NT; ++T) {
    const unsigned char* buf = lds[T & 3];
    bool st = (T + 3) < NT;

    // ---- phase 0: MFMA cluster 0 (a0,a1 x b0,b1); read a2,a3; stage 2 parts
    if (st) { STAGE(T + 3, 0); STAGE(T + 3, 1); }
    v8i a2 = FRAG(buf, arow + 2 * 2048);
    v8i a3 = FRAG(buf, arow + 3 * 2048);
    __builtin_amdgcn_s_setprio(1);
    acc[0][0] = MFMA_SC(a0, b0, acc[0][0]);
    acc[0][1] = MFMA_SC(a0, b1, acc[0][1]);
    acc[1][0] = MFMA_SC(a1, b0, acc[1][0]);
    acc[1][1] = MFMA_SC(a1, b1, acc[1][1]);
    __builtin_amdgcn_s_setprio(0);

    // ---- phase 1: MFMA cluster 1 (a2,a3 x b0,b1); read next tile's frags
    if (st) { STAGE(T + 3, 2); STAGE(T + 3, 3); }
    v8i a0n, a1n, b0n, b1n;
    if (T < NT - 1) {
      const unsigned char* bufn = lds[(T + 1) & 3];
      a0n = FRAG(bufn, arow);
      a1n = FRAG(bufn, arow + 2048);
      b0n = FRAG(bufn, brow_o);
      b1n = FRAG(bufn, brow_o + 2048);
    }
    __builtin_amdgcn_s_setprio(1);
    acc[2][0] = MFMA_SC(a2, b0, acc[2][0]);
    acc[2][1] = MFMA_SC(a2, b1, acc[2][1]);
    acc[3][0] = MFMA_SC(a3, b0, acc[3][0]);
    acc[3][1] = MFMA_SC(a3, b1, acc[3][1]);
    __builtin_amdgcn_s_setprio(0);

    // ---- boundary: drain loads for tile T+2 (read during tile T+1), keep
    // T+3's 4 loads in flight; single barrier per tile.
    if (st) {
      asm volatile("s_waitcnt vmcnt(4)" ::: "memory");
      __builtin_amdgcn_s_barrier();
    } else if (T == NT - 3) {
      asm volatile("s_waitcnt vmcnt(0)" ::: "memory");
      __builtin_amdgcn_s_barrier();
    }
    // T >= NT-2: no more staging anywhere; no barrier needed.

    a0 = a0n; a1 = a1n; b0 = b0n; b1 = b1n;
  }

  // epilogue: 32x32 C/D map: col = lane&31, row = (reg&3)+8*(reg>>2)+4*(lane>>5)
  float scale = load_scale(amax_bits) * load_scale(amax_bits + 1);
  float* Cp = C + (size_t)(brow + wm * 128 + khalf * 4) * N_DIM +
              (bcol + wn * 64 + r5);
#pragma unroll
  for (int m = 0; m < 4; ++m)
#pragma unroll
    for (int r = 0; r < 16; ++r) {
      size_t ro = (size_t)(m * 32 + (r & 3) + 8 * (r >> 2)) * N_DIM;
#pragma unroll
      for (int n = 0; n < 2; ++n)
        Cp[ro + n * 32] = acc[m][n][r] * scale;
    }
}

// ----------------------------------------------------------------- launch ---
extern "C" void kernel_launch(void* const* d_in, const int* in_sizes, int n_in,
                              void* d_out, int out_size, void* d_ws,
                              size_t ws_size, hipStream_t stream) {
  const float* in1 = (const float*)d_in[0];
  const float* in2 = (const float*)d_in[1];
  float* out = (float*)d_out;
  unsigned char* ws = (unsigned char*)d_ws;

  const int R = in_sizes[0] / K_DIM;  // 16384
  const size_t qa_bytes = (size_t)R * K_DIM;
  const size_t qb_bytes = (size_t)N_DIM * K_DIM;
  const size_t need = 256 + qa_bytes + qb_bytes;
  if (ws_size < need) {
    fprintf(stderr, "kernel_launch: ws_size %zu < needed %zu\n", ws_size, need);
    return;
  }
  unsigned* amax = (unsigned*)ws;
  unsigned char* q1 = ws + 256;
  unsigned char* q2t = q1 + qa_bytes;

  hipMemsetAsync(ws, 0, 8, stream);
  amax_kernel<<<2048, 256, 0, stream>>>((const float4*)in1, in_sizes[0] / 4, amax);
  amax_kernel<<<1024, 256, 0, stream>>>((const float4*)in2, in_sizes[1] / 4, amax + 1);
  quant1_kernel<<<2048, 256, 0, stream>>>((const float4*)in1, (uint4*)q1, amax,
                                          in_sizes[0] / 16);
  quant2t_kernel<<<(K_DIM / 64) * (N_DIM / 64), 256, 0, stream>>>(in2, q2t, amax + 1);
  gemm_fp8_kernel<<<(R / 256) * (N_DIM / 256), 512, 0, stream>>>(q1, q2t, out, amax);
}